// Round 3
// baseline (1033.655 us; speedup 1.0000x reference)
//
#include <hip/hip_runtime.h>

#define EPS_ 1e-6f

// ---------- K0: weights fp32 [o][c] -> fp32 transposed [c][o] ----------
__global__ __launch_bounds__(256) void k_cvt(
    const float* __restrict__ Wq, const float* __restrict__ Wk,
    const float* __restrict__ Wv, const float* __restrict__ Wo,
    float* __restrict__ fWqT, float* __restrict__ fWkT,
    float* __restrict__ fWvT, float* __restrict__ fWoT){
  int i = blockIdx.x*256 + threadIdx.x;   // 65536 total
  int o = i >> 8, c = i & 255;
  int j = c*256 + o;
  fWqT[j] = Wq[i]; fWkT[j] = Wk[i];
  fWvT[j] = Wv[i]; fWoT[j] = Wo[i];
}

// ---------- K1: style LN + K/V projection. out layout [b][n][o] ----------
__global__ __launch_bounds__(256) void k_style_kv(
    const float* __restrict__ s, const float* __restrict__ lns_w,
    const float* __restrict__ lns_b,
    const float* __restrict__ fWkT, const float* __restrict__ fWvT,
    float* __restrict__ kbufT, float* __restrict__ vbufT){
  __shared__ float sn[256];
  __shared__ float red[8];
  int t = threadIdx.x;
  int bn = blockIdx.x;                       // b*256 + n
  float v0 = s[(size_t)bn*256 + t];
  float s1 = v0, s2 = v0*v0;
  #pragma unroll
  for (int off=32; off; off>>=1){ s1 += __shfl_down(s1, off); s2 += __shfl_down(s2, off); }
  int lane = t & 63, wv = t >> 6;
  if (lane == 0){ red[wv] = s1; red[4+wv] = s2; }
  __syncthreads();
  float a = red[0]+red[1]+red[2]+red[3];
  float q = red[4]+red[5]+red[6]+red[7];
  float mu = a * (1.f/256.f);
  float rstd = rsqrtf(q*(1.f/256.f) - mu*mu + EPS_);
  sn[t] = (v0 - mu)*rstd*lns_w[t] + lns_b[t];
  __syncthreads();
  float ak0=0.f, ak1=0.f, av0=0.f, av1=0.f;
  for (int c=0; c<256; c+=2){
    float u0 = sn[c], u1 = sn[c+1];
    ak0 += fWkT[c*256+t]*u0;  ak1 += fWkT[(c+1)*256+t]*u1;
    av0 += fWvT[c*256+t]*u0;  av1 += fWvT[(c+1)*256+t]*u1;
  }
  kbufT[(size_t)bn*256 + t] = ak0+ak1;
  vbufT[(size_t)bn*256 + t] = av0+av1;
}

// ---------- K2: fused LN(x) -> Q GEMM -> attention -> Wo GEMM -> residual ----
// One block = 32 spatial positions. 256 threads: pp = t&31 (position),
// g8 = t>>5 (channel-segment / head index, 0..7).
__global__ __launch_bounds__(256) void k_fused(
    const float* __restrict__ x, const float* __restrict__ ln_w,
    const float* __restrict__ ln_b,
    const float* __restrict__ fWqT, const float* __restrict__ fWoT,
    const float* __restrict__ kbufT, const float* __restrict__ vbufT,
    const float* __restrict__ bo, float* __restrict__ out){
  __shared__ float bufA[256*32];   // 32 KB: stats -> hn -> att
  __shared__ float bufB[256*32];   // 32 KB: q
  int t  = threadIdx.x;
  int tile = blockIdx.x;           // 0..1023
  int b  = tile >> 9;
  int p0 = (tile & 511) << 5;
  int pp = t & 31;
  int g8 = t >> 5;                 // 0..7
  const float* xb = x + ((size_t)b << 22) + p0 + pp;

  // ---- phase 1: per-position channel stats (each thread: 32 channels) ----
  float s1 = 0.f, s2 = 0.f;
  for (int k = 0; k < 32; ++k){
    int c = g8*32 + k;
    float v = xb[(size_t)c << 14];
    s1 += v; s2 += v*v;
  }
  bufA[g8*32 + pp]       = s1;
  bufA[256 + g8*32 + pp] = s2;
  __syncthreads();
  float a = 0.f, q = 0.f;
  #pragma unroll
  for (int g = 0; g < 8; ++g){ a += bufA[g*32 + pp]; q += bufA[256 + g*32 + pp]; }
  float mu   = a * (1.f/256.f);
  float rstd = rsqrtf(q*(1.f/256.f) - mu*mu + EPS_);
  __syncthreads();                 // stats region dead; reuse bufA as hn

  // ---- phase 2: normalize into LDS hn[c][pp] ----
  for (int k = 0; k < 32; ++k){
    int c = k*8 + g8;
    float v = xb[(size_t)c << 14];
    bufA[c*32 + pp] = (v - mu)*rstd*ln_w[c] + ln_b[c];
  }
  __syncthreads();

  // ---- phase 3: Q GEMM: q[o][pp] = sum_c WqT[c][o]*hn[c][pp] ----
  {
    float acc[4][8];
    #pragma unroll
    for (int og = 0; og < 4; ++og)
      #pragma unroll
      for (int j = 0; j < 8; ++j) acc[og][j] = 0.f;
    for (int c = 0; c < 256; ++c){
      float hv = bufA[c*32 + pp];
      const float* wr = fWqT + c*256 + g8*8;
      #pragma unroll
      for (int og = 0; og < 4; ++og){
        float4 w0 = *(const float4*)(wr + og*64);
        float4 w1 = *(const float4*)(wr + og*64 + 4);
        acc[og][0] += w0.x*hv; acc[og][1] += w0.y*hv;
        acc[og][2] += w0.z*hv; acc[og][3] += w0.w*hv;
        acc[og][4] += w1.x*hv; acc[og][5] += w1.y*hv;
        acc[og][6] += w1.z*hv; acc[og][7] += w1.w*hv;
      }
    }
    #pragma unroll
    for (int og = 0; og < 4; ++og)
      #pragma unroll
      for (int j = 0; j < 8; ++j)
        bufB[(og*64 + g8*8 + j)*32 + pp] = acc[og][j];
  }
  __syncthreads();                 // q ready in bufB; bufA (hn) now dead

  // ---- phase 4: attention, head h = g8, position pp ----
  {
    int h = g8;
    float qr[32];
    #pragma unroll
    for (int d = 0; d < 32; ++d) qr[d] = bufB[(h*32 + d)*32 + pp];
    const float* kb = kbufT + ((size_t)b << 16) + h*32;
    const float* vb = vbufT + ((size_t)b << 16) + h*32;
    float m = -1e30f, l = 0.f;
    float acc[32];
    #pragma unroll
    for (int d = 0; d < 32; ++d) acc[d] = 0.f;
    const float scale = 0.1767766952966369f;   // 32^-0.5
    for (int n = 0; n < 256; ++n){
      const float4* kr = (const float4*)(kb + n*256);
      float d0=0.f, d1=0.f, d2=0.f, d3=0.f;
      #pragma unroll
      for (int j = 0; j < 8; ++j){
        float4 kv = kr[j];
        d0 += kv.x*qr[4*j];   d1 += kv.y*qr[4*j+1];
        d2 += kv.z*qr[4*j+2]; d3 += kv.w*qr[4*j+3];
      }
      float sc = ((d0+d1)+(d2+d3))*scale;
      if (sc > m){                             // lazy-max online softmax
        float corr = __expf(m - sc);           // first hit: exp(-1e30)=0
        m = sc; l *= corr;
        #pragma unroll
        for (int d = 0; d < 32; ++d) acc[d] *= corr;
      }
      float f = __expf(sc - m);
      l += f;
      const float4* vr = (const float4*)(vb + n*256);
      #pragma unroll
      for (int j = 0; j < 8; ++j){
        float4 vv = vr[j];
        acc[4*j]   += f*vv.x; acc[4*j+1] += f*vv.y;
        acc[4*j+2] += f*vv.z; acc[4*j+3] += f*vv.w;
      }
    }
    float inv = 1.f/l;
    #pragma unroll
    for (int d = 0; d < 32; ++d)
      bufA[(h*32 + d)*32 + pp] = acc[d]*inv;   // att[c][pp] into bufA
  }
  __syncthreads();

  // ---- phase 5: Wo GEMM + bias + residual, fp32 store ----
  {
    float acc[4][8];
    #pragma unroll
    for (int og = 0; og < 4; ++og)
      #pragma unroll
      for (int j = 0; j < 8; ++j) acc[og][j] = 0.f;
    for (int c = 0; c < 256; ++c){
      float hv = bufA[c*32 + pp];
      const float* wr = fWoT + c*256 + g8*8;
      #pragma unroll
      for (int og = 0; og < 4; ++og){
        float4 w0 = *(const float4*)(wr + og*64);
        float4 w1 = *(const float4*)(wr + og*64 + 4);
        acc[og][0] += w0.x*hv; acc[og][1] += w0.y*hv;
        acc[og][2] += w0.z*hv; acc[og][3] += w0.w*hv;
        acc[og][4] += w1.x*hv; acc[og][5] += w1.y*hv;
        acc[og][6] += w1.z*hv; acc[og][7] += w1.w*hv;
      }
    }
    float* ob = out + ((size_t)b << 22) + p0 + pp;
    #pragma unroll
    for (int og = 0; og < 4; ++og)
      #pragma unroll
      for (int j = 0; j < 8; ++j){
        int o = og*64 + g8*8 + j;
        size_t idx = (size_t)o << 14;
        ob[idx] = acc[og][j] + bo[o] + xb[idx];
      }
  }
}

extern "C" void kernel_launch(void* const* d_in, const int* in_sizes, int n_in,
                              void* d_out, int out_size, void* d_ws, size_t ws_size,
                              hipStream_t stream) {
  const float* x     = (const float*)d_in[0];
  const float* s     = (const float*)d_in[1];
  const float* ln_w  = (const float*)d_in[2];
  const float* ln_b  = (const float*)d_in[3];
  const float* lns_w = (const float*)d_in[4];
  const float* lns_b = (const float*)d_in[5];
  const float* Wq    = (const float*)d_in[6];
  const float* Wk    = (const float*)d_in[7];
  const float* Wv    = (const float*)d_in[8];
  const float* Wo    = (const float*)d_in[9];
  const float* bo    = (const float*)d_in[10];
  float* out = (float*)d_out;

  float* ws    = (float*)d_ws;
  float* fWqT  = ws;                 //  65536 floats
  float* fWkT  = fWqT + 65536;       //  65536
  float* fWvT  = fWkT + 65536;       //  65536
  float* fWoT  = fWvT + 65536;       //  65536
  float* kbufT = fWoT + 65536;       // 131072  [b][n][o]
  float* vbufT = kbufT + 131072;     // 131072
  // total ws use: 524288 floats = 2.0 MB

  k_cvt     <<<256,  256, 0, stream>>>(Wq, Wk, Wv, Wo, fWqT, fWkT, fWvT, fWoT);
  k_style_kv<<<512,  256, 0, stream>>>(s, lns_w, lns_b, fWkT, fWvT, kbufT, vbufT);
  k_fused   <<<1024, 256, 0, stream>>>(x, ln_w, ln_b, fWqT, fWoT, kbufT, vbufT, bo, out);
}

// Round 4
// 218.718 us; speedup vs baseline: 4.7260x; 4.7260x over previous
//
#include <hip/hip_runtime.h>

#define EPS_ 1e-6f

typedef __attribute__((ext_vector_type(8))) short bf16x8;
typedef __attribute__((ext_vector_type(4))) float f32x4;

__device__ __forceinline__ unsigned short f2b(float f){
  union { float f; unsigned int u; } v; v.f = f;
  unsigned int r = v.u + 0x7fffu + ((v.u >> 16) & 1u);
  return (unsigned short)(r >> 16);
}

// ---------- K0: weight prep ----------
// fWkT/fWvT: fp32 [c][o] transposed (for k_kv's coalesced fp32 proj)
// bWq/bWo:   bf16 [o][c] (A-operand layout: lane m=o=l16, k=c contiguous)
__global__ __launch_bounds__(256) void k_cvt(
    const float* __restrict__ Wq, const float* __restrict__ Wk,
    const float* __restrict__ Wv, const float* __restrict__ Wo,
    float* __restrict__ fWkT, float* __restrict__ fWvT,
    unsigned short* __restrict__ bWq, unsigned short* __restrict__ bWo){
  int i = blockIdx.x*256 + threadIdx.x;     // 65536
  int o = i >> 8, c = i & 255;
  fWkT[c*256+o] = Wk[i];
  fWvT[c*256+o] = Wv[i];
  bWq[i] = f2b(Wq[i]);
  bWo[i] = f2b(Wo[i]);
}

// ---------- K1: style LN + K/V proj (fp32), bf16 out ----------
// Kb: [bh][n][d] (d-contig)   Vb: [bh][d][n] (n-contig)
__global__ __launch_bounds__(256) void k_kv(
    const float* __restrict__ s, const float* __restrict__ lns_w,
    const float* __restrict__ lns_b,
    const float* __restrict__ fWkT, const float* __restrict__ fWvT,
    unsigned short* __restrict__ Kb, unsigned short* __restrict__ Vb){
  __shared__ float sn[256];
  __shared__ float red[8];
  int t = threadIdx.x;
  int bn = blockIdx.x;                      // b*256 + n
  float v0 = s[(size_t)bn*256 + t];
  float s1 = v0, s2 = v0*v0;
  #pragma unroll
  for (int off=32; off; off>>=1){ s1 += __shfl_down(s1, off); s2 += __shfl_down(s2, off); }
  int lane = t & 63, wv = t >> 6;
  if (lane == 0){ red[wv] = s1; red[4+wv] = s2; }
  __syncthreads();
  float a = red[0]+red[1]+red[2]+red[3];
  float q = red[4]+red[5]+red[6]+red[7];
  float mu = a * (1.f/256.f);
  float rstd = rsqrtf(q*(1.f/256.f) - mu*mu + EPS_);
  sn[t] = (v0 - mu)*rstd*lns_w[t] + lns_b[t];
  __syncthreads();
  float ak0=0.f, ak1=0.f, av0=0.f, av1=0.f;
  for (int c=0; c<256; c+=2){
    float u0 = sn[c], u1 = sn[c+1];
    ak0 += fWkT[c*256+t]*u0;  ak1 += fWkT[(c+1)*256+t]*u1;
    av0 += fWvT[c*256+t]*u0;  av1 += fWvT[(c+1)*256+t]*u1;
  }
  int b = bn >> 8, n = bn & 255, h = t >> 5, d = t & 31;
  Kb[(((size_t)b*8+h)*256 + n)*32 + d] = f2b(ak0+ak1);
  Vb[(((size_t)b*8+h)*32 + d)*256 + n] = f2b(av0+av1);
}

// ---------- K2: LN(x) + Q-proj MFMA. qbuf: [bh][p][d] bf16 ----------
// block = 64 positions; 4 waves; wave w owns o-range [w*64, w*64+64)
__global__ __launch_bounds__(256) void k_lnq(
    const float* __restrict__ x, const float* __restrict__ ln_w,
    const float* __restrict__ ln_b, const unsigned short* __restrict__ bWq,
    unsigned short* __restrict__ qbuf){
  __shared__ unsigned short hn[64*264];     // [p][256c + 8 pad]
  __shared__ float st[512];
  int t = threadIdx.x;
  int tile = blockIdx.x;
  int b = tile >> 8, p0 = (tile & 255) << 6;
  int pp = t & 63, seg = t >> 6;
  const float* xb = x + ((size_t)b << 22) + p0 + pp;
  float s1=0.f, s2=0.f;
  for (int k=0;k<64;++k){
    float v = xb[(size_t)(seg*64+k) << 14];
    s1 += v; s2 += v*v;
  }
  st[seg*64+pp] = s1; st[256+seg*64+pp] = s2;
  __syncthreads();
  float a = st[pp]+st[64+pp]+st[128+pp]+st[192+pp];
  float q = st[256+pp]+st[320+pp]+st[384+pp]+st[448+pp];
  float mu = a*(1.f/256.f);
  float rstd = rsqrtf(q*(1.f/256.f)-mu*mu+EPS_);
  for (int k=0;k<32;++k){
    int c = seg*64 + 2*k;
    float v0 = (xb[(size_t)c<<14]    -mu)*rstd*ln_w[c]   + ln_b[c];
    float v1 = (xb[(size_t)(c+1)<<14]-mu)*rstd*ln_w[c+1] + ln_b[c+1];
    unsigned int pk = (unsigned int)f2b(v0) | ((unsigned int)f2b(v1)<<16);
    *(unsigned int*)&hn[pp*264 + c] = pk;
  }
  __syncthreads();
  // MFMA: q[o][p] = sum_c Wq[o][c]*hn[c][p]
  int lane = t & 63, w = t >> 6;
  int quad = lane >> 4, l16 = lane & 15;
  f32x4 acc[4][4];
  #pragma unroll
  for (int ot=0;ot<4;++ot)
    #pragma unroll
    for (int pt=0;pt<4;++pt) acc[ot][pt] = (f32x4){0.f,0.f,0.f,0.f};
  const unsigned short* wq = bWq + (size_t)(w*64 + l16)*256 + quad*8;
  for (int ks=0; ks<8; ++ks){
    bf16x8 bfr[4], afr[4];
    #pragma unroll
    for (int pt=0;pt<4;++pt)
      bfr[pt] = *(const bf16x8*)&hn[(pt*16+l16)*264 + ks*32 + quad*8];
    #pragma unroll
    for (int ot=0;ot<4;++ot)
      afr[ot] = *(const bf16x8*)(wq + ot*16*256 + ks*32);
    #pragma unroll
    for (int ot=0;ot<4;++ot)
      #pragma unroll
      for (int pt=0;pt<4;++pt)
        acc[ot][pt] = __builtin_amdgcn_mfma_f32_16x16x32_bf16(afr[ot], bfr[pt], acc[ot][pt], 0,0,0);
  }
  #pragma unroll
  for (int ot=0;ot<4;++ot){
    int o = w*64 + ot*16 + quad*4;          // 4 consecutive o, within one head
    int h = o >> 5, db = o & 31;
    #pragma unroll
    for (int pt=0;pt<4;++pt){
      int p = p0 + pt*16 + l16;
      unsigned short pk[4];
      #pragma unroll
      for (int r=0;r<4;++r) pk[r] = f2b(acc[ot][pt][r]);
      *(uint2*)&qbuf[(((size_t)b*8+h)*16384 + p)*32 + db] = *(uint2*)pk;
    }
  }
}

// ---------- K3: attention. wave = 16 positions x 1 head ----------
__global__ __launch_bounds__(256) void k_attn(
    const unsigned short* __restrict__ qbuf, const unsigned short* __restrict__ Kb,
    const unsigned short* __restrict__ Vb, unsigned short* __restrict__ abuf){
  __shared__ unsigned short Pt[4*16*264];   // per-wave P transpose [p][n+pad]
  int t = threadIdx.x;
  int bh = blockIdx.y;
  int b = bh >> 3, h = bh & 7;
  int w = t >> 6, lane = t & 63, quad = lane >> 4, l16 = lane & 15;
  int p0 = blockIdx.x*64 + w*16;
  // A-frag: q[m=p][k=d]
  bf16x8 qf = *(const bf16x8*)&qbuf[((size_t)bh*16384 + p0 + l16)*32 + quad*8];
  f32x4 sc[16];
  const unsigned short* kb = Kb + (size_t)bh*256*32 + quad*8;
  #pragma unroll
  for (int nt=0;nt<16;++nt){
    bf16x8 kf = *(const bf16x8*)(kb + (size_t)(nt*16+l16)*32);
    f32x4 z = {0.f,0.f,0.f,0.f};
    sc[nt] = __builtin_amdgcn_mfma_f32_16x16x32_bf16(qf, kf, z, 0,0,0);
  }
  const float scale = 0.17677669529663689f;  // 32^-0.5
  float mx[4] = {-1e30f,-1e30f,-1e30f,-1e30f};
  #pragma unroll
  for (int nt=0;nt<16;++nt)
    #pragma unroll
    for (int r=0;r<4;++r) mx[r] = fmaxf(mx[r], sc[nt][r]);
  #pragma unroll
  for (int m=1;m<16;m<<=1)
    #pragma unroll
    for (int r=0;r<4;++r) mx[r] = fmaxf(mx[r], __shfl_xor(mx[r], m, 64));
  float sm[4] = {0.f,0.f,0.f,0.f};
  #pragma unroll
  for (int nt=0;nt<16;++nt)
    #pragma unroll
    for (int r=0;r<4;++r){
      float p = __expf((sc[nt][r]-mx[r])*scale);
      sc[nt][r] = p; sm[r] += p;
    }
  #pragma unroll
  for (int m=1;m<16;m<<=1)
    #pragma unroll
    for (int r=0;r<4;++r) sm[r] += __shfl_xor(sm[r], m, 64);
  float inv[4];
  #pragma unroll
  for (int r=0;r<4;++r) inv[r] = 1.f/sm[r];
  // P (D-layout: row p=quad*4+r, col n=nt*16+l16) -> LDS [p][n]
  unsigned short* Pw = Pt + w*16*264;
  #pragma unroll
  for (int nt=0;nt<16;++nt)
    #pragma unroll
    for (int r=0;r<4;++r)
      Pw[(quad*4+r)*264 + nt*16 + l16] = f2b(sc[nt][r]*inv[r]);
  __syncthreads();                           // (wave-local, but cheap & safe)
  // PV: att[p][d] = sum_n P[p][n] V[n][d]
  f32x4 av[2] = {{0.f,0.f,0.f,0.f},{0.f,0.f,0.f,0.f}};
  const unsigned short* vb = Vb + (size_t)bh*32*256 + quad*8;
  for (int ks=0; ks<8; ++ks){
    bf16x8 pf = *(const bf16x8*)&Pw[l16*264 + ks*32 + quad*8];
    #pragma unroll
    for (int dt=0; dt<2; ++dt){
      bf16x8 vf = *(const bf16x8*)(vb + (size_t)(dt*16+l16)*256 + ks*32);
      av[dt] = __builtin_amdgcn_mfma_f32_16x16x32_bf16(pf, vf, av[dt], 0,0,0);
    }
  }
  // store att -> abuf [b][p][c] bf16
  #pragma unroll
  for (int dt=0; dt<2; ++dt)
    #pragma unroll
    for (int r=0;r<4;++r)
      abuf[((size_t)b*16384 + p0 + quad*4 + r)*256 + h*32 + dt*16 + l16] = f2b(av[dt][r]);
}

// ---------- K4: Wo MFMA + bias + residual ----------
__global__ __launch_bounds__(256) void k_out(
    const unsigned short* __restrict__ abuf, const unsigned short* __restrict__ bWo,
    const float* __restrict__ bo, const float* __restrict__ x,
    float* __restrict__ out){
  int t = threadIdx.x;
  int tile = blockIdx.x;
  int b = tile >> 8, p0 = (tile & 255) << 6;
  int w = t >> 6, lane = t & 63, quad = lane >> 4, l16 = lane & 15;
  f32x4 acc[4][4];
  #pragma unroll
  for (int ot=0;ot<4;++ot)
    #pragma unroll
    for (int pt=0;pt<4;++pt) acc[ot][pt] = (f32x4){0.f,0.f,0.f,0.f};
  const unsigned short* wo = bWo + (size_t)(w*64 + l16)*256 + quad*8;
  const unsigned short* ab = abuf + ((size_t)b*16384 + p0 + l16)*256 + quad*8;
  for (int ks=0; ks<8; ++ks){
    bf16x8 bfr[4], afr[4];
    #pragma unroll
    for (int pt=0;pt<4;++pt)
      bfr[pt] = *(const bf16x8*)(ab + (size_t)pt*16*256 + ks*32);
    #pragma unroll
    for (int ot=0;ot<4;++ot)
      afr[ot] = *(const bf16x8*)(wo + (size_t)ot*16*256 + ks*32);
    #pragma unroll
    for (int ot=0;ot<4;++ot)
      #pragma unroll
      for (int pt=0;pt<4;++pt)
        acc[ot][pt] = __builtin_amdgcn_mfma_f32_16x16x32_bf16(afr[ot], bfr[pt], acc[ot][pt], 0,0,0);
  }
  #pragma unroll
  for (int ot=0;ot<4;++ot){
    int o = w*64 + ot*16 + quad*4;
    #pragma unroll
    for (int pt=0;pt<4;++pt){
      int p = p0 + pt*16 + l16;
      #pragma unroll
      for (int r=0;r<4;++r){
        size_t idx = (((size_t)b*256 + o + r) << 14) + p;
        out[idx] = acc[ot][pt][r] + bo[o+r] + x[idx];
      }
    }
  }
}

extern "C" void kernel_launch(void* const* d_in, const int* in_sizes, int n_in,
                              void* d_out, int out_size, void* d_ws, size_t ws_size,
                              hipStream_t stream) {
  const float* x     = (const float*)d_in[0];
  const float* s     = (const float*)d_in[1];
  const float* ln_w  = (const float*)d_in[2];
  const float* ln_b  = (const float*)d_in[3];
  const float* lns_w = (const float*)d_in[4];
  const float* lns_b = (const float*)d_in[5];
  const float* Wq    = (const float*)d_in[6];
  const float* Wk    = (const float*)d_in[7];
  const float* Wv    = (const float*)d_in[8];
  const float* Wo    = (const float*)d_in[9];
  const float* bo    = (const float*)d_in[10];
  float* out = (float*)d_out;

  // ws: abuf(16.78MB) + fp32 K/V weightT (0.5MB) + bf16 weights (0.25MB) + K/V (0.5MB) ~ 18MB
  unsigned short* abuf = (unsigned short*)d_ws;            // 8388608 us
  float* fWkT = (float*)(abuf + 8388608);                  // 65536 f
  float* fWvT = fWkT + 65536;                              // 65536 f
  unsigned short* bWq = (unsigned short*)(fWvT + 65536);   // 65536 us
  unsigned short* bWo = bWq + 65536;                       // 65536 us
  unsigned short* Kb  = bWo + 65536;                       // 131072 us
  unsigned short* Vb  = Kb + 131072;                       // 131072 us
  // qbuf: first 16.78 MB of d_out (fully overwritten by k_out afterwards)
  unsigned short* qbuf = (unsigned short*)d_out;

  k_cvt <<<256, 256, 0, stream>>>(Wq, Wk, Wv, Wo, fWkT, fWvT, bWq, bWo);
  k_kv  <<<512, 256, 0, stream>>>(s, lns_w, lns_b, fWkT, fWvT, Kb, Vb);
  k_lnq <<<512, 256, 0, stream>>>(x, ln_w, ln_b, bWq, qbuf);
  k_attn<<<dim3(256,16), 256, 0, stream>>>(qbuf, Kb, Vb, abuf);
  k_out <<<512, 256, 0, stream>>>(abuf, bWo, bo, x, out);
}